// Round 5
// baseline (304.095 us; speedup 1.0000x reference)
//
#include <hip/hip_runtime.h>
#include <stdint.h>

// Problem constants: B=8, N=2048, F_in=F_out=512
#define NB 8
#define NN 2048
#define NF 512
#define TOTN (NB * NN)   // 16384 nodes total

typedef unsigned short u16;
typedef short bf16x8 __attribute__((ext_vector_type(8)));
typedef float f32x4 __attribute__((ext_vector_type(4)));

__device__ __forceinline__ u16 f2bf(float x) {
  unsigned u = __float_as_uint(x);
  unsigned r = 0x7FFFu + ((u >> 16) & 1u);
  return (u16)((u + r) >> 16);
}

__device__ __forceinline__ void gl2lds16(const void* g, void* l) {
  // async global->LDS, 16B per lane; LDS dst = wave-uniform base + lane*16
  __builtin_amdgcn_global_load_lds((const __attribute__((address_space(1))) void*)g,
                                   (__attribute__((address_space(3))) void*)l,
                                   16, 0, 0);
}

// slab swizzle: within a 16-row chunk, data (row rc, k-quarter q) lives at
// slot = rc*4 + (q ^ ((rc>>1)&3)), 16 B per slot.  (verified conflict-free R3/R4)
// XCD mapping heuristic: linear blockIdx % 8 -> XCD (round-robin). All kernels
// below pin batch z to XCD z so hS slabs + bitmask stay in one XCD's L2.

// ---------------------------------------------------------------------------
// K1: convert text (8.4M fp32) -> bf16, and W -> W^T bf16.
// ---------------------------------------------------------------------------
__global__ __launch_bounds__(256) void conv_kernel(
    const float* __restrict__ text, const float* __restrict__ W,
    u16* __restrict__ text_bf, u16* __restrict__ Wt) {
  int blk = blockIdx.x;
  if (blk < 8192) {
    int idx = blk * 256 + threadIdx.x;
    float4 v = ((const float4*)text)[idx];
    ushort4 o;
    o.x = f2bf(v.x); o.y = f2bf(v.y); o.z = f2bf(v.z); o.w = f2bf(v.w);
    ((ushort4*)text_bf)[idx] = o;
  } else {
    int t = (blk - 8192) * 256 + threadIdx.x;
    int o = t >> 9, f = t & 511;
    Wt[o * NF + f] = f2bf(W[f * NF + o]);
  }
}

// ---------------------------------------------------------------------------
// K2: pack adj (int32 0/1) -> bitmask, 32 elems/thread. 134 MB -> 4 MB.
// bm layout: [node_row 16384][word 64] u32. XCD-pinned: block bid handles
// words of batch z = bid&7 so bm rows are written on their consumer XCD.
// ---------------------------------------------------------------------------
__global__ __launch_bounds__(256) void pack_kernel(
    const int* __restrict__ adj, uint32_t* __restrict__ bm) {
  int bid = blockIdx.x;               // 4096 blocks
  int z = bid & 7, idx = bid >> 3;    // idx 0..511
  int gid = z * 131072 + idx * 256 + threadIdx.x;  // word index
  const int4* p = (const int4*)(adj + (size_t)gid * 32);
  uint32_t bits = 0;
#pragma unroll
  for (int c = 0; c < 8; ++c) {
    int4 a = p[c];
    bits |= (uint32_t)(a.x != 0) << (c * 4 + 0);
    bits |= (uint32_t)(a.y != 0) << (c * 4 + 1);
    bits |= (uint32_t)(a.z != 0) << (c * 4 + 2);
    bits |= (uint32_t)(a.w != 0) << (c * 4 + 3);
  }
  bm[gid] = bits;
}

// ---------------------------------------------------------------------------
// K3: GEMM1 hidden[o][node] -> pre-swizzled slabs + fused s/d score epilogue.
// hS layout: [z 8][oh 2][kc 64][16KB slab image]; image = 16 chunks(16 o-rows)
// x swizzled slots. XCD-pinned: block bid covers node-range of z = bid&7, so
// slab writes land dirty in the XCD L2 that will consume them.
// ---------------------------------------------------------------------------
__global__ __launch_bounds__(256) void gemm1_kernel(
    const u16* __restrict__ A,   // Wt [512][512]
    const u16* __restrict__ Bt,  // text_bf [16384][512]
    const float* __restrict__ bias, const float* __restrict__ a_src,
    const float* __restrict__ a_dst, u16* __restrict__ hS,
    float* __restrict__ s, float* __restrict__ d) {
  __shared__ u16 Alds[128 * 32];
  __shared__ u16 Blds[128 * 32];

  const int bid = blockIdx.x;                  // 512 blocks
  const int zx = bid & 7, u = (bid >> 3) & 15, bm_ = bid >> 7;
  const int bn = zx * 16 + u;                  // node-tile: rows of batch zx
  const int t = threadIdx.x, wave = t >> 6, lane = t & 63;
  const int wm = (wave >> 1) * 64, wn = (wave & 1) * 64;

  f32x4 acc[4][4];
#pragma unroll
  for (int i = 0; i < 4; ++i)
#pragma unroll
    for (int j = 0; j < 4; ++j) acc[i][j] = (f32x4){0.f, 0.f, 0.f, 0.f};

  const int rowA0 = bm_ * 128, rowB0 = bn * 128;
  const int srow = (lane >> 2);
  const int scol = (lane & 3) * 8;

  for (int kt = 0; kt < NF; kt += 32) {
#pragma unroll
    for (int q = 0; q < 2; ++q) {
      int r = wave * 32 + q * 16;
      gl2lds16(A + (size_t)(rowA0 + r + srow) * NF + (kt + scol), &Alds[r * 32]);
    }
#pragma unroll
    for (int q = 0; q < 2; ++q) {
      int r = wave * 32 + q * 16;
      gl2lds16(Bt + (size_t)(rowB0 + r + srow) * NF + (kt + scol), &Blds[r * 32]);
    }
    __syncthreads();

    const int fr = lane & 15;
    const int k0 = (lane >> 4) * 8;
    bf16x8 af[4], bfr[4];
#pragma unroll
    for (int i = 0; i < 4; ++i)
      af[i] = *(const bf16x8*)&Alds[(wm + i * 16 + fr) * 32 + k0];
#pragma unroll
    for (int j = 0; j < 4; ++j)
      bfr[j] = *(const bf16x8*)&Blds[(wn + j * 16 + fr) * 32 + k0];
#pragma unroll
    for (int i = 0; i < 4; ++i)
#pragma unroll
      for (int j = 0; j < 4; ++j)
        acc[i][j] = __builtin_amdgcn_mfma_f32_16x16x32_bf16(af[i], bfr[j],
                                                            acc[i][j], 0, 0, 0);
    __syncthreads();
  }

  const int quad = lane >> 4, ln16 = lane & 15;
  float sa[4] = {0.f, 0.f, 0.f, 0.f}, da[4] = {0.f, 0.f, 0.f, 0.f};
#pragma unroll
  for (int i = 0; i < 4; ++i) {
    int m0 = bm_ * 128 + wm + i * 16 + quad * 4;
#pragma unroll
    for (int r = 0; r < 4; ++r) {
      int m = m0 + r;
      float bv = bias[m];
      float asv = a_src[m], adv = a_dst[m];
      int oh = m >> 8, och = (m >> 4) & 15, rc = m & 15;
#pragma unroll
      for (int j = 0; j < 4; ++j) {
        int n = bn * 128 + wn + j * 16 + ln16;
        float h = acc[i][j][r] + bv;
        int zz = n >> 11, nz = n & 2047;
        int kc = nz >> 5, kin = nz & 31;
        size_t off = ((((size_t)zz * 2 + oh) * 64 + kc) << 13)  // slab, u16 units
                     + (och << 9)
                     + ((size_t)(rc * 4 + ((kin >> 3) ^ ((rc >> 1) & 3))) << 3)
                     + (kin & 7);
        hS[off] = f2bf(h);
        sa[j] = fmaf(h, asv, sa[j]);
        da[j] = fmaf(h, adv, da[j]);
      }
    }
  }
#pragma unroll
  for (int j = 0; j < 4; ++j) {
    float v = sa[j] + __shfl_xor(sa[j], 16, 64);
    v += __shfl_xor(v, 32, 64);
    float w2 = da[j] + __shfl_xor(da[j], 16, 64);
    w2 += __shfl_xor(w2, 32, 64);
    if (quad == 0) {
      int n = bn * 128 + wn + j * 16 + ln16;
      atomicAdd(&s[n], v);
      atomicAdd(&d[n], w2);
    }
  }
}

// ---------------------------------------------------------------------------
// K4 (fused): out[z,i,o] = (1/l_i)*sum_j exp(lrelu(s_i+d_j))·[!adj]·h[j][o]
// 64(i) x 256(o) tile, 4 waves, BK=64, 512 blocks (2/CU). XCD-pinned z=bid&7:
// each XCD streams only its own 2 MB of slabs + 512 KB bitmask -> local L2 hits.
// ---------------------------------------------------------------------------
__global__ __launch_bounds__(256, 2) void fused_attn_kernel(
    const uint32_t* __restrict__ bm, const float* __restrict__ s,
    const float* __restrict__ d, const u16* __restrict__ hS,
    float* __restrict__ out) {
  __shared__ u16 Blds[16384];      // 32 KB = 2 kc-slabs
  __shared__ u16 Plds[4096];       // 8 KB = 2 k-half images
  __shared__ float lpart[256];
  __shared__ float linv_lds[64];

  const int bid = blockIdx.x;               // 512 blocks
  const int z = bid & 7;
  const int rest = bid >> 3;                // 0..63
  const int oh = rest >> 5;
  const int i0 = (rest & 31) * 64;
  const int t = threadIdx.x, wave = t >> 6, lane = t & 63;
  const int quad = lane >> 4, ln16 = lane & 15;

  // P-gen mapping: 4 threads per i-row, 16 k each
  const int pr = t >> 2;           // 0..63
  const int ko = (t & 3) * 16;     // 0,16,32,48
  const float si = s[z * NN + i0 + pr];
  const uint32_t* bmrow = bm + (size_t)(z * NN + i0 + pr) * 64;
  const float* db = d + z * NN;

  const char* slabB = (const char*)hS + (size_t)(z * 2 + oh) * 1048576;

  f32x4 acc[4][4];
#pragma unroll
  for (int i = 0; i < 4; ++i)
#pragma unroll
    for (int j = 0; j < 4; ++j) acc[i][j] = (f32x4){0.f, 0.f, 0.f, 0.f};

  // prefetch regs for kt=0
  uint32_t bw = bmrow[ko >> 5];
  float4 dv[4];
#pragma unroll
  for (int c = 0; c < 4; ++c) dv[c] = *(const float4*)&db[ko + c * 4];

  const int fslot = ln16 * 4 + (quad ^ ((ln16 >> 1) & 3));
  const int prc = pr & 15, pch = pr >> 4;
  const int ph = ko >> 5, pq0 = (ko >> 3) & 3;  // k-half, first quarter (0 or 2)
  char* pbase = (char*)Plds + ph * 4096 + pch * 1024;
  char* pdst0 = pbase + (prc * 4 + (pq0 ^ ((prc >> 1) & 3))) * 16;
  char* pdst1 = pbase + (prc * 4 + ((pq0 + 1) ^ ((prc >> 1) & 3))) * 16;

  float lsum = 0.f;

  for (int kt = 0; kt < NN; kt += 64) {
    // ---- P values for k = kt+ko .. +16 from prefetched regs ----
    uint32_t bits16 = (bw >> (ko & 16)) & 0xFFFFu;
    u16 pk[16];
#pragma unroll
    for (int cc = 0; cc < 4; ++cc) {
      float4 dq = dv[cc];
#pragma unroll
      for (int e = 0; e < 4; ++e) {
        float dj = (e == 0) ? dq.x : (e == 1) ? dq.y : (e == 2) ? dq.z : dq.w;
        float x = si + dj;
        float xm = fmaxf(x, 0.2f * x);
        float p = ((bits16 >> (cc * 4 + e)) & 1u) ? 0.f : __expf(xm);
        lsum += p;
        pk[cc * 4 + e] = f2bf(p);
      }
    }

    __syncthreads();  // (1) frags of previous iter consumed

    *(int4*)pdst0 = *(int4*)&pk[0];
    *(int4*)pdst1 = *(int4*)&pk[8];

    // ---- stage 2 contiguous 16 KB slabs (kc0, kc0+1) ----
    {
      const char* gB = slabB + (size_t)kt * 512;  // kt/64 * 32768
#pragma unroll
      for (int c = 0; c < 8; ++c) {
        int boff = (c * 4 + wave) * 1024;
        gl2lds16(gB + boff + lane * 16, (char*)Blds + boff);
      }
    }
    __syncthreads();  // (2) P visible + B staged

    // ---- prefetch next kt (L2-hot, overlaps MFMA) ----
    if (kt + 64 < NN) {
      bw = bmrow[((kt + 64) >> 5) + (ko >> 5)];
#pragma unroll
      for (int c = 0; c < 4; ++c)
        dv[c] = *(const float4*)&db[kt + 64 + ko + c * 4];
    }

    // ---- fragments + MFMA: 2 k-halves x 4i x 4j ----
#pragma unroll
    for (int h = 0; h < 2; ++h) {
      bf16x8 af[4], bfv[4];
#pragma unroll
      for (int i = 0; i < 4; ++i)
        af[i] = *(const bf16x8*)((const char*)Plds + h * 4096 + i * 1024 + fslot * 16);
#pragma unroll
      for (int j = 0; j < 4; ++j)
        bfv[j] = *(const bf16x8*)((const char*)Blds + h * 16384 +
                                  (wave * 4 + j) * 1024 + fslot * 16);
#pragma unroll
      for (int i = 0; i < 4; ++i)
#pragma unroll
        for (int j = 0; j < 4; ++j)
          acc[i][j] = __builtin_amdgcn_mfma_f32_16x16x32_bf16(af[i], bfv[j],
                                                              acc[i][j], 0, 0, 0);
    }
  }

  // ---- row sums -> 1/l (block covers full K, sums complete) ----
  lpart[pr * 4 + (t & 3)] = lsum;
  __syncthreads();
  if (t < 64) {
    const float* lp = &lpart[t * 4];
    linv_lds[t] = 1.0f / ((lp[0] + lp[1]) + (lp[2] + lp[3]));
  }
  __syncthreads();

  // ---- epilogue: C/D layout col=lane&15, row=quad*4+reg ----
#pragma unroll
  for (int i = 0; i < 4; ++i) {
#pragma unroll
    for (int r = 0; r < 4; ++r) {
      int m = i * 16 + quad * 4 + r;
      float sc = linv_lds[m];
      float* ob = out + ((size_t)(z * NN) + i0 + m) * NF + oh * 256 + wave * 64;
#pragma unroll
      for (int j = 0; j < 4; ++j) ob[j * 16 + ln16] = acc[i][j][r] * sc;
    }
  }
}

// ---------------------------------------------------------------------------
// launch
// ---------------------------------------------------------------------------
extern "C" void kernel_launch(void* const* d_in, const int* in_sizes, int n_in,
                              void* d_out, int out_size, void* d_ws,
                              size_t ws_size, hipStream_t stream) {
  const float* text  = (const float*)d_in[0];   // [8,2048,512] fp32
  const int*   adj   = (const int*)d_in[1];     // [8,2048,2048] int32
  const float* W     = (const float*)d_in[2];   // [512,512] fp32
  const float* bias  = (const float*)d_in[3];   // [512] fp32
  const float* a_src = (const float*)d_in[4];   // [512] fp32
  const float* a_dst = (const float*)d_in[5];   // [512] fp32
  float* out = (float*)d_out;                   // [8,2048,512] fp32

  // ws layout (bytes), ~38.4 MB
  char* ws = (char*)d_ws;
  u16*      text_bf = (u16*)(ws + 0);            // 16,777,216
  u16*      Wt      = (u16*)(ws + 16777216);     //    524,288
  u16*      hS      = (u16*)(ws + 17301504);     // 16,777,216  slabs
  float*    s       = (float*)(ws + 34078720);   //     65,536
  float*    d       = (float*)(ws + 34144256);   //     65,536
  uint32_t* bmask   = (uint32_t*)(ws + 34209792);// 4,194,304

  hipMemsetAsync(s, 0, 131072, stream);          // zero s,d (contiguous)

  conv_kernel<<<9216, 256, 0, stream>>>(text, W, text_bf, Wt);
  pack_kernel<<<4096, 256, 0, stream>>>(adj, bmask);

  gemm1_kernel<<<512, 256, 0, stream>>>(Wt, text_bf, bias, a_src, a_dst, hS, s, d);

  fused_attn_kernel<<<512, 256, 0, stream>>>(bmask, s, d, hS, out);
}

// Round 6
// 303.485 us; speedup vs baseline: 1.0020x; 1.0020x over previous
//
#include <hip/hip_runtime.h>
#include <stdint.h>

// Problem constants: B=8, N=2048, F_in=F_out=512
#define NB 8
#define NN 2048
#define NF 512
#define TOTN (NB * NN)   // 16384 nodes total

typedef unsigned short u16;
typedef short bf16x8 __attribute__((ext_vector_type(8)));
typedef float f32x4 __attribute__((ext_vector_type(4)));

__device__ __forceinline__ u16 f2bf(float x) {
  unsigned u = __float_as_uint(x);
  unsigned r = 0x7FFFu + ((u >> 16) & 1u);
  return (u16)((u + r) >> 16);
}

__device__ __forceinline__ void gl2lds16(const void* g, void* l) {
  __builtin_amdgcn_global_load_lds((const __attribute__((address_space(1))) void*)g,
                                   (__attribute__((address_space(3))) void*)l,
                                   16, 0, 0);
}

// Bg layout (B-operand, fragment-major): [z 8][kc 64][oc 32][lane 64][8 u16]
//   lane = kq*16 + oln holds B[o = oc*16+oln][k = kc*32 + kq*8 .. +8]
// -> a wave's B-frag load is ONE coalesced 16 B/lane global_load_dwordx4.
// P LDS swizzle (verified conflict-free R3-R5): within a 16-row chunk,
//   (row rc, k-quarter q) -> slot = rc*4 + (q ^ ((rc>>1)&3)), 16 B/slot.

// ---------------------------------------------------------------------------
// K1: convert text (8.4M fp32) -> bf16, and W -> W^T bf16.
// ---------------------------------------------------------------------------
__global__ __launch_bounds__(256) void conv_kernel(
    const float* __restrict__ text, const float* __restrict__ W,
    u16* __restrict__ text_bf, u16* __restrict__ Wt) {
  int blk = blockIdx.x;
  if (blk < 8192) {
    int idx = blk * 256 + threadIdx.x;
    float4 v = ((const float4*)text)[idx];
    ushort4 o;
    o.x = f2bf(v.x); o.y = f2bf(v.y); o.z = f2bf(v.z); o.w = f2bf(v.w);
    ((ushort4*)text_bf)[idx] = o;
  } else {
    int t = (blk - 8192) * 256 + threadIdx.x;
    int o = t >> 9, f = t & 511;
    Wt[o * NF + f] = f2bf(W[f * NF + o]);
  }
}

// ---------------------------------------------------------------------------
// K2: pack adj (int32 0/1) -> bitmask. 134 MB -> 4 MB. XCD-pinned z=bid&7.
// ---------------------------------------------------------------------------
__global__ __launch_bounds__(256) void pack_kernel(
    const int* __restrict__ adj, uint32_t* __restrict__ bm) {
  int bid = blockIdx.x;               // 4096 blocks
  int z = bid & 7, idx = bid >> 3;
  int gid = z * 131072 + idx * 256 + threadIdx.x;
  const int4* p = (const int4*)(adj + (size_t)gid * 32);
  uint32_t bits = 0;
#pragma unroll
  for (int c = 0; c < 8; ++c) {
    int4 a = p[c];
    bits |= (uint32_t)(a.x != 0) << (c * 4 + 0);
    bits |= (uint32_t)(a.y != 0) << (c * 4 + 1);
    bits |= (uint32_t)(a.z != 0) << (c * 4 + 2);
    bits |= (uint32_t)(a.w != 0) << (c * 4 + 3);
  }
  bm[gid] = bits;
}

// ---------------------------------------------------------------------------
// K3: GEMM1 hidden -> Bg fragment-major layout + fused s/d score epilogue.
// XCD-pinned: block bid covers node-range of z = bid&7.
// ---------------------------------------------------------------------------
__global__ __launch_bounds__(256) void gemm1_kernel(
    const u16* __restrict__ A,   // Wt [512][512]
    const u16* __restrict__ Bt,  // text_bf [16384][512]
    const float* __restrict__ bias, const float* __restrict__ a_src,
    const float* __restrict__ a_dst, u16* __restrict__ Bg,
    float* __restrict__ s, float* __restrict__ d) {
  __shared__ u16 Alds[128 * 32];
  __shared__ u16 Blds[128 * 32];

  const int bid = blockIdx.x;                  // 512 blocks
  const int zx = bid & 7, u = (bid >> 3) & 15, bm_ = bid >> 7;
  const int bn = zx * 16 + u;
  const int t = threadIdx.x, wave = t >> 6, lane = t & 63;
  const int wm = (wave >> 1) * 64, wn = (wave & 1) * 64;

  f32x4 acc[4][4];
#pragma unroll
  for (int i = 0; i < 4; ++i)
#pragma unroll
    for (int j = 0; j < 4; ++j) acc[i][j] = (f32x4){0.f, 0.f, 0.f, 0.f};

  const int rowA0 = bm_ * 128, rowB0 = bn * 128;
  const int srow = (lane >> 2);
  const int scol = (lane & 3) * 8;

  for (int kt = 0; kt < NF; kt += 32) {
#pragma unroll
    for (int q = 0; q < 2; ++q) {
      int r = wave * 32 + q * 16;
      gl2lds16(A + (size_t)(rowA0 + r + srow) * NF + (kt + scol), &Alds[r * 32]);
    }
#pragma unroll
    for (int q = 0; q < 2; ++q) {
      int r = wave * 32 + q * 16;
      gl2lds16(Bt + (size_t)(rowB0 + r + srow) * NF + (kt + scol), &Blds[r * 32]);
    }
    __syncthreads();

    const int fr = lane & 15;
    const int k0 = (lane >> 4) * 8;
    bf16x8 af[4], bfr[4];
#pragma unroll
    for (int i = 0; i < 4; ++i)
      af[i] = *(const bf16x8*)&Alds[(wm + i * 16 + fr) * 32 + k0];
#pragma unroll
    for (int j = 0; j < 4; ++j)
      bfr[j] = *(const bf16x8*)&Blds[(wn + j * 16 + fr) * 32 + k0];
#pragma unroll
    for (int i = 0; i < 4; ++i)
#pragma unroll
      for (int j = 0; j < 4; ++j)
        acc[i][j] = __builtin_amdgcn_mfma_f32_16x16x32_bf16(af[i], bfr[j],
                                                            acc[i][j], 0, 0, 0);
    __syncthreads();
  }

  const int quad = lane >> 4, ln16 = lane & 15;
  float sa[4] = {0.f, 0.f, 0.f, 0.f}, da[4] = {0.f, 0.f, 0.f, 0.f};
#pragma unroll
  for (int i = 0; i < 4; ++i) {
    int m0 = bm_ * 128 + wm + i * 16 + quad * 4;
#pragma unroll
    for (int r = 0; r < 4; ++r) {
      int m = m0 + r;
      float bv = bias[m];
      float asv = a_src[m], adv = a_dst[m];
      int oc = m >> 4, oln = m & 15;
#pragma unroll
      for (int j = 0; j < 4; ++j) {
        int n = bn * 128 + wn + j * 16 + ln16;
        float h = acc[i][j][r] + bv;
        int zz = n >> 11, nz = n & 2047;
        int kc = nz >> 5, kq = (nz >> 3) & 3, ke = nz & 7;
        size_t off = ((size_t)zz << 20) + (((size_t)kc * 32 + oc) << 9) +
                     ((kq * 16 + oln) << 3) + ke;
        Bg[off] = f2bf(h);
        sa[j] = fmaf(h, asv, sa[j]);
        da[j] = fmaf(h, adv, da[j]);
      }
    }
  }
#pragma unroll
  for (int j = 0; j < 4; ++j) {
    float v = sa[j] + __shfl_xor(sa[j], 16, 64);
    v += __shfl_xor(v, 32, 64);
    float w2 = da[j] + __shfl_xor(da[j], 16, 64);
    w2 += __shfl_xor(w2, 32, 64);
    if (quad == 0) {
      int n = bn * 128 + wn + j * 16 + ln16;
      atomicAdd(&s[n], v);
      atomicAdd(&d[n], w2);
    }
  }
}

// ---------------------------------------------------------------------------
// K4 (fused): out[z,i,o] = (1/l_i)*sum_j exp(lrelu(s_i+d_j))·[!adj]·h[j][o]
// 512 threads (8 waves), wave tile 64i x 64o, full o=512/block, BK=64,
// 256 blocks (1/CU), z pinned. B-frags loaded DIRECTLY global->VGPR (no LDS,
// no staging barrier). P double-buffered in LDS -> ONE barrier per iter.
// ---------------------------------------------------------------------------
__global__ __launch_bounds__(512, 2) void fused_attn_kernel(
    const uint32_t* __restrict__ bm, const float* __restrict__ s,
    const float* __restrict__ d, const u16* __restrict__ Bg,
    float* __restrict__ out) {
  __shared__ u16 Plds[2][4096];    // [parity][half 2][chunk 4][slot 64][8]
  __shared__ float lpart[512];
  __shared__ float linv_lds[64];

  const int bid = blockIdx.x;      // 256 blocks
  const int z = bid & 7;
  const int i0 = (bid >> 3) * 64;
  const int t = threadIdx.x, wave = t >> 6, lane = t & 63;
  const int quad = lane >> 4, ln16 = lane & 15;

  // P-gen mapping: 8 threads/row, 8 k each
  const int pr = t >> 3;           // 0..63
  const int ko = (t & 7) * 8;      // 0..56
  const float si = s[z * NN + i0 + pr];
  const uint32_t* bmrow = bm + (size_t)(z * NN + i0 + pr) * 64;
  const float* db = d + z * NN;

  const u16* BgZ = Bg + ((size_t)z << 20);

  f32x4 acc[4][4];
#pragma unroll
  for (int i = 0; i < 4; ++i)
#pragma unroll
    for (int j = 0; j < 4; ++j) acc[i][j] = (f32x4){0.f, 0.f, 0.f, 0.f};

  // prefetch regs for kt=0
  uint32_t bw = bmrow[ko >> 5];
  float4 dv0 = *(const float4*)&db[ko];
  float4 dv1 = *(const float4*)&db[ko + 4];

  // P write address (swizzled), fixed per thread up to parity
  const int prc = pr & 15, pch = pr >> 4;
  const int ph = ko >> 5, pq = (ko >> 3) & 3;
  const int pwoff = ph * 2048 + pch * 512 +
                    (prc * 4 + (pq ^ ((prc >> 1) & 3))) * 8;  // u16 units
  const int fslot = ln16 * 4 + (quad ^ ((ln16 >> 1) & 3));

  float lsum = 0.f;
  int par = 0;

  for (int kt = 0; kt < NN; kt += 64, par ^= 1) {
    // ---- P-gen: 8 values from prefetched regs ----
    uint32_t bits8 = (bw >> (ko & 31)) & 0xFFu;
    float dva[8];
    *(float4*)&dva[0] = dv0;
    *(float4*)&dva[4] = dv1;
    u16 pk[8];
#pragma unroll
    for (int e = 0; e < 8; ++e) {
      float x = si + dva[e];
      float xm = fmaxf(x, 0.2f * x);
      float p = ((bits8 >> e) & 1u) ? 0.f : __expf(xm);
      lsum += p;
      pk[e] = f2bf(p);
    }
    *(int4*)((u16*)Plds + par * 4096 + pwoff) = *(int4*)pk;

    __syncthreads();  // P[par] visible; the ONLY barrier in the K-loop

    // ---- B-frags straight from global (coalesced 16 B/lane, L2-hot) ----
    const int kc0 = kt >> 5;
    bf16x8 bfr[2][4];
#pragma unroll
    for (int h = 0; h < 2; ++h)
#pragma unroll
      for (int j = 0; j < 4; ++j)
        bfr[h][j] = *(const bf16x8*)&BgZ[(((size_t)(kc0 + h) * 32 +
                                           (wave * 4 + j)) << 9) + lane * 8];

    // ---- prefetch next iter's d/bm (L2-hot, consumed next iter) ----
    if (kt + 64 < NN) {
      bw = bmrow[((kt + 64) >> 5) + (ko >> 5)];
      dv0 = *(const float4*)&db[kt + 64 + ko];
      dv1 = *(const float4*)&db[kt + 64 + ko + 4];
    }

    // ---- A-frags from LDS, then MFMA (h=0 first: consumes earliest loads) ----
    bf16x8 af[2][4];
#pragma unroll
    for (int h = 0; h < 2; ++h)
#pragma unroll
      for (int i = 0; i < 4; ++i)
        af[h][i] = *(const bf16x8*)((const u16*)Plds + par * 4096 + h * 2048 +
                                    i * 512 + fslot * 8);
#pragma unroll
    for (int h = 0; h < 2; ++h)
#pragma unroll
      for (int i = 0; i < 4; ++i)
#pragma unroll
        for (int j = 0; j < 4; ++j)
          acc[i][j] = __builtin_amdgcn_mfma_f32_16x16x32_bf16(af[h][i],
                                                              bfr[h][j],
                                                              acc[i][j], 0, 0, 0);
  }

  // ---- row sums -> 1/l ----
  lpart[pr * 8 + (t & 7)] = lsum;
  __syncthreads();
  if (t < 64) {
    const float* lp = &lpart[t * 8];
    float tot = ((lp[0] + lp[1]) + (lp[2] + lp[3])) +
                ((lp[4] + lp[5]) + (lp[6] + lp[7]));
    linv_lds[t] = 1.0f / tot;
  }
  __syncthreads();

  // ---- epilogue: C/D layout col=lane&15, row=quad*4+reg ----
#pragma unroll
  for (int i = 0; i < 4; ++i) {
#pragma unroll
    for (int r = 0; r < 4; ++r) {
      int m = i * 16 + quad * 4 + r;
      float sc = linv_lds[m];
      float* ob = out + ((size_t)(z * NN) + i0 + m) * NF + wave * 64;
#pragma unroll
      for (int j = 0; j < 4; ++j) ob[j * 16 + ln16] = acc[i][j][r] * sc;
    }
  }
}

// ---------------------------------------------------------------------------
// launch
// ---------------------------------------------------------------------------
extern "C" void kernel_launch(void* const* d_in, const int* in_sizes, int n_in,
                              void* d_out, int out_size, void* d_ws,
                              size_t ws_size, hipStream_t stream) {
  const float* text  = (const float*)d_in[0];   // [8,2048,512] fp32
  const int*   adj   = (const int*)d_in[1];     // [8,2048,2048] int32
  const float* W     = (const float*)d_in[2];   // [512,512] fp32
  const float* bias  = (const float*)d_in[3];   // [512] fp32
  const float* a_src = (const float*)d_in[4];   // [512] fp32
  const float* a_dst = (const float*)d_in[5];   // [512] fp32
  float* out = (float*)d_out;                   // [8,2048,512] fp32

  // ws layout (bytes), ~38.4 MB
  char* ws = (char*)d_ws;
  u16*      text_bf = (u16*)(ws + 0);            // 16,777,216
  u16*      Wt      = (u16*)(ws + 16777216);     //    524,288
  u16*      Bg      = (u16*)(ws + 17301504);     // 16,777,216  frag-major
  float*    s       = (float*)(ws + 34078720);   //     65,536
  float*    d       = (float*)(ws + 34144256);   //     65,536
  uint32_t* bmask   = (uint32_t*)(ws + 34209792);// 4,194,304

  hipMemsetAsync(s, 0, 131072, stream);          // zero s,d (contiguous)

  conv_kernel<<<9216, 256, 0, stream>>>(text, W, text_bf, Wt);
  pack_kernel<<<4096, 256, 0, stream>>>(adj, bmask);

  gemm1_kernel<<<512, 256, 0, stream>>>(Wt, text_bf, bias, a_src, a_dst, Bg, s, d);

  fused_attn_kernel<<<256, 512, 0, stream>>>(bmask, s, d, Bg, out);
}